// Round 1
// baseline (1384.976 us; speedup 1.0000x reference)
//
#include <hip/hip_runtime.h>

#define LN_EPS 1e-5f

// ---- scatter: S[tgt] += feat[src], feat is [N,128] ----
__global__ __launch_bounds__(256) void scatter_feat128(
    const float* __restrict__ feat,
    const int* __restrict__ src,
    const int* __restrict__ tgt,
    float* __restrict__ S, int E) {
  int e = blockIdx.x * 2 + (threadIdx.x >> 7);
  if (e >= E) return;
  int f = threadIdx.x & 127;
  int s = src[e], t = tgt[e];
  atomicAdd(&S[t * 128 + f], feat[s * 128 + f]);
}

// ---- scatter: SE[tgt] += ef[e] (16 wide), deg[tgt] += 1 ----
__global__ __launch_bounds__(256) void scatter_edge(
    const float* __restrict__ ef,
    const int* __restrict__ tgt,
    float* __restrict__ SE, float* __restrict__ deg, int E) {
  int e = blockIdx.x * 16 + (threadIdx.x >> 4);
  if (e >= E) return;
  int f = threadIdx.x & 15;
  int t = tgt[e];
  atomicAdd(&SE[t * 16 + f], ef[e * 16 + f]);
  if (f == 0) atomicAdd(&deg[t], 1.0f);
}

// ---- layer 0: h = relu(LN(x@Ws + bs + (SX/deg)@Wm_x + (SE/deg)@Wm_e + [deg>0]bm)) ----
// 128 threads (thread j = output feature j), NPB nodes per block.
template <int NPB>
__global__ __launch_bounds__(128) void layer0_kernel(
    const float* __restrict__ x, const float* __restrict__ SX,
    const float* __restrict__ SE, const float* __restrict__ deg,
    const float* __restrict__ Ws, const float* __restrict__ bs,
    const float* __restrict__ Wm, const float* __restrict__ bm,
    const float* __restrict__ gam, const float* __restrict__ bet,
    float* __restrict__ h, int N) {
  __shared__ float u[NPB][272];
  __shared__ float dgs[NPB];
  __shared__ float wred[2][2][NPB];  // [sum|sumsq][wave][node]
  int j = threadIdx.x;
  int n0 = blockIdx.x * NPB;
  for (int m = 0; m < NPB; ++m) {
    int n = n0 + m;
    if (n < N) {
      float dg = deg[n];
      float inv = dg > 0.f ? 1.f / dg : 0.f;
      if (j == 0) dgs[m] = dg;
      u[m][j]       = x[(size_t)n * 128 + j];
      u[m][128 + j] = SX[(size_t)n * 128 + j] * inv;
      if (j < 16) u[m][256 + j] = SE[(size_t)n * 16 + j] * inv;
    } else {
      if (j == 0) dgs[m] = 0.f;
      u[m][j] = 0.f; u[m][128 + j] = 0.f;
      if (j < 16) u[m][256 + j] = 0.f;
    }
  }
  __syncthreads();
  float bsj = bs[j], bmj = bm[j];
  float acc[NPB];
  #pragma unroll
  for (int m = 0; m < NPB; ++m) acc[m] = bsj + (dgs[m] > 0.f ? bmj : 0.f);
  #pragma unroll 4
  for (int k = 0; k < 128; ++k) {
    float w = Ws[k * 128 + j];
    #pragma unroll
    for (int m = 0; m < NPB; ++m) acc[m] = fmaf(u[m][k], w, acc[m]);
  }
  #pragma unroll 4
  for (int k = 0; k < 144; ++k) {
    float w = Wm[k * 128 + j];
    #pragma unroll
    for (int m = 0; m < NPB; ++m) acc[m] = fmaf(u[m][128 + k], w, acc[m]);
  }
  // LayerNorm over 128 features (2 waves) + ReLU
  int wid = j >> 6;
  #pragma unroll
  for (int m = 0; m < NPB; ++m) {
    float v = acc[m], v2 = v * v;
    #pragma unroll
    for (int off = 32; off; off >>= 1) {
      v  += __shfl_xor(v, off);
      v2 += __shfl_xor(v2, off);
    }
    if ((j & 63) == 0) { wred[0][wid][m] = v; wred[1][wid][m] = v2; }
  }
  __syncthreads();
  float gj = gam[j], bj = bet[j];
  for (int m = 0; m < NPB; ++m) {
    int n = n0 + m;
    if (n >= N) break;
    float s1 = wred[0][0][m] + wred[0][1][m];
    float s2 = wred[1][0][m] + wred[1][1][m];
    float mean = s1 * (1.f / 128.f);
    float var = s2 * (1.f / 128.f) - mean * mean;
    float y = (acc[m] - mean) * rsqrtf(var + LN_EPS) * gj + bj;
    h[(size_t)n * 128 + j] = fmaxf(y, 0.f);
  }
}

// ---- layer 1 + fused pooling atomics. 64 threads (1 wave), NPB nodes/block ----
template <int NPB>
__global__ __launch_bounds__(64) void layer1_kernel(
    const float* __restrict__ h, const float* __restrict__ SH,
    const float* __restrict__ SE, const float* __restrict__ deg,
    const float* __restrict__ Ws, const float* __restrict__ bs,
    const float* __restrict__ Wm, const float* __restrict__ bm,
    const float* __restrict__ gam, const float* __restrict__ bet,
    const int* __restrict__ batch,
    float* __restrict__ node_emb, float* __restrict__ pooled,
    float* __restrict__ counts, int N) {
  __shared__ float u[NPB][272];
  __shared__ float dgs[NPB];
  int j = threadIdx.x;  // 0..63
  int n0 = blockIdx.x * NPB;
  for (int m = 0; m < NPB; ++m) {
    int n = n0 + m;
    if (n < N) {
      float dg = deg[n];
      float inv = dg > 0.f ? 1.f / dg : 0.f;
      if (j == 0) dgs[m] = dg;
      u[m][j]       = h[(size_t)n * 128 + j];
      u[m][64 + j]  = h[(size_t)n * 128 + 64 + j];
      u[m][128 + j] = SH[(size_t)n * 128 + j] * inv;
      u[m][192 + j] = SH[(size_t)n * 128 + 64 + j] * inv;
      if (j < 16) u[m][256 + j] = SE[(size_t)n * 16 + j] * inv;
    } else {
      if (j == 0) dgs[m] = 0.f;
      u[m][j] = 0.f; u[m][64 + j] = 0.f; u[m][128 + j] = 0.f; u[m][192 + j] = 0.f;
      if (j < 16) u[m][256 + j] = 0.f;
    }
  }
  __syncthreads();
  float bsj = bs[j], bmj = bm[j];
  float acc[NPB];
  #pragma unroll
  for (int m = 0; m < NPB; ++m) acc[m] = bsj + (dgs[m] > 0.f ? bmj : 0.f);
  #pragma unroll 4
  for (int k = 0; k < 128; ++k) {
    float w = Ws[k * 64 + j];
    #pragma unroll
    for (int m = 0; m < NPB; ++m) acc[m] = fmaf(u[m][k], w, acc[m]);
  }
  #pragma unroll 4
  for (int k = 0; k < 144; ++k) {
    float w = Wm[k * 64 + j];
    #pragma unroll
    for (int m = 0; m < NPB; ++m) acc[m] = fmaf(u[m][128 + k], w, acc[m]);
  }
  float gj = gam[j], bj = bet[j];
  for (int m = 0; m < NPB; ++m) {
    int n = n0 + m;
    if (n >= N) break;
    float v = acc[m], v2 = v * v;
    #pragma unroll
    for (int off = 32; off; off >>= 1) {
      v  += __shfl_xor(v, off);
      v2 += __shfl_xor(v2, off);
    }
    float mean = v * (1.f / 64.f);
    float var = v2 * (1.f / 64.f) - mean * mean;
    float y = (acc[m] - mean) * rsqrtf(var + LN_EPS) * gj + bj;
    node_emb[(size_t)n * 64 + j] = y;
    int grp = batch[n];
    atomicAdd(&pooled[grp * 64 + j], y);
    if (j == 0) atomicAdd(&counts[grp], 1.0f);
  }
}

__global__ __launch_bounds__(64) void graph_mean(
    const float* __restrict__ pooled, const float* __restrict__ counts,
    float* __restrict__ out) {
  int g = blockIdx.x, j = threadIdx.x;
  float inv = 1.f / fmaxf(counts[g], 1.f);
  out[g * 64 + j] = pooled[g * 64 + j] * inv;
}

extern "C" void kernel_launch(void* const* d_in, const int* in_sizes, int n_in,
                              void* d_out, int out_size, void* d_ws, size_t ws_size,
                              hipStream_t stream) {
  const float* x   = (const float*)d_in[0];
  const float* ef  = (const float*)d_in[1];
  const float* Ws0 = (const float*)d_in[2];
  const float* bs0 = (const float*)d_in[3];
  const float* Wm0 = (const float*)d_in[4];
  const float* bm0 = (const float*)d_in[5];
  const float* g0  = (const float*)d_in[6];
  const float* be0 = (const float*)d_in[7];
  const float* Ws1 = (const float*)d_in[8];
  const float* bs1 = (const float*)d_in[9];
  const float* Wm1 = (const float*)d_in[10];
  const float* bm1 = (const float*)d_in[11];
  const float* g1  = (const float*)d_in[12];
  const float* be1 = (const float*)d_in[13];
  const int* edge_index = (const int*)d_in[14];
  const int* batch = (const int*)d_in[15];

  const int N = in_sizes[0] / 128;
  const int E = in_sizes[14] / 2;
  const int G = 64;  // num_graphs fixed by setup_inputs
  const int* src = edge_index;
  const int* tgt = edge_index + E;

  char* ws = (char*)d_ws;
  size_t off = 0;
  auto alloc = [&](size_t bytes) -> void* {
    void* p = ws + off;
    off = (off + bytes + 255) & ~(size_t)255;
    return p;
  };
  float* SX     = (float*)alloc((size_t)N * 128 * 4);  // reused as SH after layer 0
  float* SE     = (float*)alloc((size_t)N * 16 * 4);
  float* deg    = (float*)alloc((size_t)N * 4);
  float* h      = (float*)alloc((size_t)N * 128 * 4);
  float* pooled = (float*)alloc((size_t)G * 64 * 4);
  float* counts = (float*)alloc((size_t)G * 4);

  hipMemsetAsync(SX, 0, (size_t)N * 128 * 4, stream);
  hipMemsetAsync(SE, 0, (size_t)N * 16 * 4, stream);
  hipMemsetAsync(deg, 0, (size_t)N * 4, stream);
  hipMemsetAsync(pooled, 0, (size_t)G * 64 * 4, stream);
  hipMemsetAsync(counts, 0, (size_t)G * 4, stream);

  scatter_edge<<<(E + 15) / 16, 256, 0, stream>>>(ef, tgt, SE, deg, E);
  scatter_feat128<<<(E + 1) / 2, 256, 0, stream>>>(x, src, tgt, SX, E);

  layer0_kernel<8><<<(N + 7) / 8, 128, 0, stream>>>(
      x, SX, SE, deg, Ws0, bs0, Wm0, bm0, g0, be0, h, N);

  // reuse SX buffer as SH
  hipMemsetAsync(SX, 0, (size_t)N * 128 * 4, stream);
  scatter_feat128<<<(E + 1) / 2, 256, 0, stream>>>(h, src, tgt, SX, E);

  layer1_kernel<8><<<(N + 7) / 8, 64, 0, stream>>>(
      h, SX, SE, deg, Ws1, bs1, Wm1, bm1, g1, be1, batch,
      (float*)d_out, pooled, counts, N);

  graph_mean<<<G, 64, 0, stream>>>(pooled, counts, (float*)d_out + (size_t)N * 64);
}